// Round 1
// baseline (856.653 us; speedup 1.0000x reference)
//
#include <hip/hip_runtime.h>
#include <cmath>

#ifndef M_PI
#define M_PI 3.14159265358979323846
#endif

constexpr int Dn = 200;
constexpr int DD = Dn * Dn;        // 40000
constexpr int NC = Dn * Dn * Dn;   // 8,000,000

// One thread per cell. mask==0 lanes skip the neighbor loop entirely
// (their output is just v2=v, p2=p+DT*v). Contact branch (~4e-6 per pair)
// is the only place velocities of neighbors are read.
__global__ __launch_bounds__(256) void dem_step_kernel(
    const float* __restrict__ gx, const float* __restrict__ gy, const float* __restrict__ gz,
    const float* __restrict__ gvx, const float* __restrict__ gvy, const float* __restrict__ gvz,
    const float* __restrict__ gm, float* __restrict__ out,
    float ETAf, float dtOverPm, float gravTerm)
{
    const int tid = blockIdx.x * 256 + threadIdx.x;
    if (tid >= NC) return;

    const int xk = tid % Dn;         // stride-1 axis
    const int t1 = tid / Dn;
    const int yj = t1 % Dn;          // stride-200 axis
    const int zi = t1 / Dn;          // stride-40000 axis

    const float X = gx[tid], Y = gy[tid], Z = gz[tid];
    const float VX = gvx[tid], VY = gvy[tid], VZ = gvz[tid];
    const float M = gm[tid];

    float fx = 0.f, fy = 0.f, fz = 0.f;

    if (M != 0.f) {
        for (int o2 = -2; o2 <= 2; ++o2) {
            int nz = zi + o2;
            nz += (nz < 0) ? Dn : 0;
            nz -= (nz >= Dn) ? Dn : 0;
            const int zb = nz * DD;
            for (int o3 = -2; o3 <= 2; ++o3) {
                int ny = yj + o3;
                ny += (ny < 0) ? Dn : 0;
                ny -= (ny >= Dn) ? Dn : 0;
                const int rowb = zb + ny * Dn;
                #pragma unroll
                for (int o4 = -2; o4 <= 2; ++o4) {
                    int nx = xk + o4;
                    nx += (nx < 0) ? Dn : 0;
                    nx -= (nx >= Dn) ? Dn : 0;
                    const int idx = rowb + nx;
                    const float dx = X - gx[idx];
                    const float dy = Y - gy[idx];
                    const float dz = Z - gz[idx];
                    const float sq = dx * dx + dy * dy + dz * dz;
                    // conservative prefilter, then exact reference condition
                    if (sq < 0.0100001f) {
                        const float dist = sqrtf(sq);
                        if (dist < 0.1f) {
                            const float d = fmaxf(dist, 1e-4f);
                            const float dvx = VX - gvx[idx];
                            const float dvy = VY - gvy[idx];
                            const float dvz = VZ - gvz[idx];
                            const float vn = ((dvx * dx + dvy * dy) + dvz * dz) / d;
                            const float coef = 2.0f * (600000.0f * (dist - 0.1f) + ETAf * vn) / d;
                            fx += coef * dx;
                            fy += coef * dy;
                            fz += coef * dz;
                        }
                    }
                }
            }
        }
    }

    // ---- wall boundary forces (left/right mutually exclusive; mask folded
    //      into the update since mask is exactly 0.0 or 1.0) ----
    float fxb = 0.f, fyb = 0.f, fzb = 0.f;
    if (X > 0.1f && X < 0.15f) fxb = 600000.0f * (0.15f - X) - ETAf * VX;
    if (X > 9.9f)              fxb = -600000.0f * (((X - 10.0f) + 0.05f) + 0.05f) - ETAf * VX;
    if (Y > 0.1f && Y < 0.15f) fyb = 600000.0f * (0.15f - Y) - ETAf * VY;
    if (Y > 9.9f)              fyb = -600000.0f * (((Y - 10.0f) + 0.05f) + 0.05f) - ETAf * VY;
    if (Z > 0.1f && Z < 0.15f) fzb = 600000.0f * (0.15f - Z) - ETAf * VZ;
    if (Z > 9.9f)              fzb = -600000.0f * (((Z - 10.0f) + 0.05f) + 0.05f) - ETAf * VZ;

    // ---- semi-implicit Euler update ----
    const float am = dtOverPm * M;
    const float vx2 = VX + am * ((-fx) + fxb);
    const float vy2 = VY + am * ((-fy) + fyb);
    const float vz2 = VZ + am * ((gravTerm - fz) + fzb);

    out[0 * NC + tid] = X + 1e-4f * vx2;
    out[1 * NC + tid] = Y + 1e-4f * vy2;
    out[2 * NC + tid] = Z + 1e-4f * vz2;
    out[3 * NC + tid] = vx2;
    out[4 * NC + tid] = vy2;
    out[5 * NC + tid] = vz2;
}

extern "C" void kernel_launch(void* const* d_in, const int* in_sizes, int n_in,
                              void* d_out, int out_size, void* d_ws, size_t ws_size,
                              hipStream_t stream) {
    const float* gx  = (const float*)d_in[0];
    const float* gy  = (const float*)d_in[1];
    const float* gz  = (const float*)d_in[2];
    const float* gvx = (const float*)d_in[3];
    const float* gvy = (const float*)d_in[4];
    const float* gvz = (const float*)d_in[5];
    const float* gm  = (const float*)d_in[6];
    float* out = (float*)d_out;

    // host-side double math, mirroring the numpy module-level constants exactly
    const double KN  = 600000.0;
    const double PM  = 4.0 / 3.0 * 3.1415 * std::pow(0.05, 3) * 2700.0;
    const double alpha = -std::log(0.5) / M_PI;
    const double gamma = alpha / std::sqrt(alpha * alpha + 1.0);
    const double ETA = 2.0 * gamma * std::sqrt(KN * PM);

    const float ETAf     = (float)ETA;
    const float dtOverPm = (float)(0.0001 / PM);
    const float gravTerm = (float)(-9.8 * PM);

    const int blocks = (NC + 255) / 256;  // 31250, exact
    dem_step_kernel<<<blocks, 256, 0, stream>>>(gx, gy, gz, gvx, gvy, gvz, gm, out,
                                                ETAf, dtOverPm, gravTerm);
}

// Round 2
// 463.929 us; speedup vs baseline: 1.8465x; 1.8465x over previous
//
#include <hip/hip_runtime.h>
#include <cmath>

#ifndef M_PI
#define M_PI 3.14159265358979323846
#endif

constexpr int Dn = 200;
constexpr int DD = Dn * Dn;        // 40000
constexpr int NC = Dn * Dn * Dn;   // 8,000,000
constexpr int RPB = 5;             // rows per block
constexpr int TPR = 50;            // threads per row (200 / 4 cells)
constexpr int NBLK = (Dn * Dn) / RPB;  // 8000 blocks (divisible by 8 -> bijective XCD swizzle)

// 4 x-cells per thread. Per stencil row: 3 aligned float4 loads per array
// (12-float window covers the 4 cells' 5-point x-neighborhoods incl. wrap).
// Inner 20 pairs/row are pure register math; contact branch (~4e-6/pair) is
// the only place neighbor velocities are read.
__global__ __launch_bounds__(256, 4) void dem_step_kernel(
    const float* __restrict__ gx, const float* __restrict__ gy, const float* __restrict__ gz,
    const float* __restrict__ gvx, const float* __restrict__ gvy, const float* __restrict__ gvz,
    const float* __restrict__ gm, float* __restrict__ out,
    float ETAf, float dtOverPm, float gravTerm)
{
    const int t = threadIdx.x;
    if (t >= RPB * TPR) return;

    // XCD-aware swizzle: each XCD gets a contiguous z-slab (L2 locality)
    const int bid = blockIdx.x;
    const int sb = (bid & 7) * (NBLK / 8) + (bid >> 3);

    const int rowid = sb * RPB + t / TPR;   // 0..39999 = zi*200 + yj
    const int lane = t % TPR;
    const int x0 = lane * 4;
    const int zi = rowid / Dn;
    const int yj = rowid % Dn;

    // ---- center cell data (4 cells) ----
    const int cbase = rowid * Dn + x0;
    const float4 X4  = *reinterpret_cast<const float4*>(gx  + cbase);
    const float4 Y4  = *reinterpret_cast<const float4*>(gy  + cbase);
    const float4 Z4  = *reinterpret_cast<const float4*>(gz  + cbase);
    const float4 VX4 = *reinterpret_cast<const float4*>(gvx + cbase);
    const float4 VY4 = *reinterpret_cast<const float4*>(gvy + cbase);
    const float4 VZ4 = *reinterpret_cast<const float4*>(gvz + cbase);
    const float4 M4  = *reinterpret_cast<const float4*>(gm  + cbase);

    const float Xc[4]  = {X4.x,  X4.y,  X4.z,  X4.w};
    const float Yc[4]  = {Y4.x,  Y4.y,  Y4.z,  Y4.w};
    const float Zc[4]  = {Z4.x,  Z4.y,  Z4.z,  Z4.w};
    const float VXc[4] = {VX4.x, VX4.y, VX4.z, VX4.w};
    const float VYc[4] = {VY4.x, VY4.y, VY4.z, VY4.w};
    const float VZc[4] = {VZ4.x, VZ4.y, VZ4.z, VZ4.w};
    const float Mc[4]  = {M4.x,  M4.y,  M4.z,  M4.w};

    // ---- precomputed wrapped row bases and x window offsets ----
    int zb[5], yb[5];
    #pragma unroll
    for (int o = 0; o < 5; ++o) {
        int zz = zi + o - 2; zz += (zz < 0) ? Dn : 0; zz -= (zz >= Dn) ? Dn : 0;
        zb[o] = zz * DD;
        int yy = yj + o - 2; yy += (yy < 0) ? Dn : 0; yy -= (yy >= Dn) ? Dn : 0;
        yb[o] = yy * Dn;
    }
    int xA = x0 - 4; if (xA < 0) xA += Dn;      // wrapped left float4
    int xC = x0 + 4; if (xC >= Dn) xC -= Dn;    // wrapped right float4

    float fxa[4] = {0.f, 0.f, 0.f, 0.f};
    float fya[4] = {0.f, 0.f, 0.f, 0.f};
    float fza[4] = {0.f, 0.f, 0.f, 0.f};

    for (int i2 = 0; i2 < 5; ++i2) {
        const int zbb = zb[i2];
        #pragma unroll
        for (int i3 = 0; i3 < 5; ++i3) {
            const int rowb = zbb + yb[i3];
            const float4 ax = *reinterpret_cast<const float4*>(gx + rowb + xA);
            const float4 bx = *reinterpret_cast<const float4*>(gx + rowb + x0);
            const float4 cx = *reinterpret_cast<const float4*>(gx + rowb + xC);
            const float4 ay = *reinterpret_cast<const float4*>(gy + rowb + xA);
            const float4 by = *reinterpret_cast<const float4*>(gy + rowb + x0);
            const float4 cy = *reinterpret_cast<const float4*>(gy + rowb + xC);
            const float4 az = *reinterpret_cast<const float4*>(gz + rowb + xA);
            const float4 bz = *reinterpret_cast<const float4*>(gz + rowb + x0);
            const float4 cz = *reinterpret_cast<const float4*>(gz + rowb + xC);

            const float rx[12] = {ax.x, ax.y, ax.z, ax.w, bx.x, bx.y, bx.z, bx.w, cx.x, cx.y, cx.z, cx.w};
            const float ry[12] = {ay.x, ay.y, ay.z, ay.w, by.x, by.y, by.z, by.w, cy.x, cy.y, cy.z, cy.w};
            const float rz[12] = {az.x, az.y, az.z, az.w, bz.x, bz.y, bz.z, bz.w, cz.x, cz.y, cz.z, cz.w};

            #pragma unroll
            for (int c = 0; c < 4; ++c) {
                #pragma unroll
                for (int o = 0; o < 5; ++o) {
                    const int n = c + o + 2;           // 2..9, compile-time
                    const float dx = Xc[c] - rx[n];
                    const float dy = Yc[c] - ry[n];
                    const float dz = Zc[c] - rz[n];
                    const float sq = dx * dx + dy * dy + dz * dz;
                    if (sq < 0.0100001f) {             // conservative prefilter
                        const float dist = sqrtf(sq);
                        if (dist < 0.1f) {             // exact reference condition
                            const float d = fmaxf(dist, 1e-4f);
                            int nxi = x0 + c + o - 2;
                            nxi += (nxi < 0) ? Dn : 0;
                            nxi -= (nxi >= Dn) ? Dn : 0;
                            const int gi = rowb + nxi;
                            const float dvx = VXc[c] - gvx[gi];
                            const float dvy = VYc[c] - gvy[gi];
                            const float dvz = VZc[c] - gvz[gi];
                            const float vn = (dvx * dx + dvy * dy + dvz * dz) / d;
                            const float coef = 2.0f * (600000.0f * (dist - 0.1f) + ETAf * vn) / d;
                            fxa[c] += coef * dx;
                            fya[c] += coef * dy;
                            fza[c] += coef * dz;
                        }
                    }
                }
            }
        }
    }

    // ---- boundary forces + semi-implicit Euler update, 4 cells ----
    float x2[4], y2[4], z2[4], vxn[4], vyn[4], vzn[4];
    #pragma unroll
    for (int c = 0; c < 4; ++c) {
        const float X = Xc[c], Y = Yc[c], Z = Zc[c];
        const float VX = VXc[c], VY = VYc[c], VZ = VZc[c];
        float fxb = 0.f, fyb = 0.f, fzb = 0.f;
        if (X > 0.1f && X < 0.15f) fxb = 600000.0f * (0.15f - X) - ETAf * VX;
        if (X > 9.9f)              fxb = -600000.0f * (((X - 10.0f) + 0.05f) + 0.05f) - ETAf * VX;
        if (Y > 0.1f && Y < 0.15f) fyb = 600000.0f * (0.15f - Y) - ETAf * VY;
        if (Y > 9.9f)              fyb = -600000.0f * (((Y - 10.0f) + 0.05f) + 0.05f) - ETAf * VY;
        if (Z > 0.1f && Z < 0.15f) fzb = 600000.0f * (0.15f - Z) - ETAf * VZ;
        if (Z > 9.9f)              fzb = -600000.0f * (((Z - 10.0f) + 0.05f) + 0.05f) - ETAf * VZ;

        const float am = dtOverPm * Mc[c];
        vxn[c] = VX + am * ((-fxa[c]) + fxb);
        vyn[c] = VY + am * ((-fya[c]) + fyb);
        vzn[c] = VZ + am * ((gravTerm - fza[c]) + fzb);
        x2[c] = X + 1e-4f * vxn[c];
        y2[c] = Y + 1e-4f * vyn[c];
        z2[c] = Z + 1e-4f * vzn[c];
    }

    *reinterpret_cast<float4*>(out + 0 * NC + cbase) = make_float4(x2[0], x2[1], x2[2], x2[3]);
    *reinterpret_cast<float4*>(out + 1 * NC + cbase) = make_float4(y2[0], y2[1], y2[2], y2[3]);
    *reinterpret_cast<float4*>(out + 2 * NC + cbase) = make_float4(z2[0], z2[1], z2[2], z2[3]);
    *reinterpret_cast<float4*>(out + 3 * NC + cbase) = make_float4(vxn[0], vxn[1], vxn[2], vxn[3]);
    *reinterpret_cast<float4*>(out + 4 * NC + cbase) = make_float4(vyn[0], vyn[1], vyn[2], vyn[3]);
    *reinterpret_cast<float4*>(out + 5 * NC + cbase) = make_float4(vzn[0], vzn[1], vzn[2], vzn[3]);
}

extern "C" void kernel_launch(void* const* d_in, const int* in_sizes, int n_in,
                              void* d_out, int out_size, void* d_ws, size_t ws_size,
                              hipStream_t stream) {
    const float* gx  = (const float*)d_in[0];
    const float* gy  = (const float*)d_in[1];
    const float* gz  = (const float*)d_in[2];
    const float* gvx = (const float*)d_in[3];
    const float* gvy = (const float*)d_in[4];
    const float* gvz = (const float*)d_in[5];
    const float* gm  = (const float*)d_in[6];
    float* out = (float*)d_out;

    const double KN  = 600000.0;
    const double PM  = 4.0 / 3.0 * 3.1415 * std::pow(0.05, 3) * 2700.0;
    const double alpha = -std::log(0.5) / M_PI;
    const double gamma = alpha / std::sqrt(alpha * alpha + 1.0);
    const double ETA = 2.0 * gamma * std::sqrt(KN * PM);

    const float ETAf     = (float)ETA;
    const float dtOverPm = (float)(0.0001 / PM);
    const float gravTerm = (float)(-9.8 * PM);

    dem_step_kernel<<<NBLK, 256, 0, stream>>>(gx, gy, gz, gvx, gvy, gvz, gm, out,
                                              ETAf, dtOverPm, gravTerm);
}

// Round 4
// 221.036 us; speedup vs baseline: 3.8756x; 2.0989x over previous
//
#include <hip/hip_runtime.h>
#include <cmath>

#ifndef M_PI
#define M_PI 3.14159265358979323846
#endif

typedef float v2f __attribute__((ext_vector_type(2)));
typedef float v4f __attribute__((ext_vector_type(4)));

constexpr int Dn = 200;
constexpr int DD = Dn * Dn;        // 40000
constexpr int NC = Dn * Dn * Dn;   // 8,000,000
constexpr int TPR = 25;            // threads per row (8 cells each)
constexpr int RPB = 10;            // rows per block (block = 250 live threads)
constexpr int NBLK = (Dn * Dn) / RPB;  // 4000, divisible by 8 -> bijective XCD swizzle
constexpr float THR = 0.0100001f;  // conservative prefilter on sq (exact test in slow path)

// compile-time component selectors (fold to direct register access under full unroll)
#define C4(v,c) ((c)==0?(v).x:(c)==1?(v).y:(c)==2?(v).z:(v).w)
#define WK(L,A,B,R,k) ((k)==0?(L).x:(k)==1?(L).y: \
                       ((k)>=2&&(k)<=5)?C4(A,(k)-2): \
                       ((k)>=6&&(k)<=9)?C4(B,(k)-6): \
                       ((k)==10?(R).x:(R).y))

__global__ __launch_bounds__(256, 2) void dem_step_kernel(
    const float* __restrict__ gx, const float* __restrict__ gy, const float* __restrict__ gz,
    const float* __restrict__ gvx, const float* __restrict__ gvy, const float* __restrict__ gvz,
    const float* __restrict__ gm, float* __restrict__ out,
    float ETAf, float dtOverPm, float gravTerm)
{
    const int t = threadIdx.x;
    if (t >= TPR * RPB) return;

    // XCD-aware swizzle: each XCD gets a contiguous z-slab
    const int bid = blockIdx.x;
    const int sb = (bid & 7) * (NBLK / 8) + (bid >> 3);

    const int rowid = sb * RPB + t / TPR;   // zi*200 + yj  (z uniform per block)
    const int x0 = (t % TPR) * 8;
    const int zi = rowid / Dn;
    const int yj = rowid % Dn;
    const int cbase = rowid * Dn + x0;

    // ---- center positions, packed per cell-pair {2cp, 2cp+1} ----
    const float4 Xa = *reinterpret_cast<const float4*>(gx + cbase);
    const float4 Xb = *reinterpret_cast<const float4*>(gx + cbase + 4);
    const float4 Ya = *reinterpret_cast<const float4*>(gy + cbase);
    const float4 Yb = *reinterpret_cast<const float4*>(gy + cbase + 4);
    const float4 Za = *reinterpret_cast<const float4*>(gz + cbase);
    const float4 Zb = *reinterpret_cast<const float4*>(gz + cbase + 4);

    v2f Xp[4] = {{Xa.x,Xa.y},{Xa.z,Xa.w},{Xb.x,Xb.y},{Xb.z,Xb.w}};
    v2f Yp[4] = {{Ya.x,Ya.y},{Ya.z,Ya.w},{Yb.x,Yb.y},{Yb.z,Yb.w}};
    v2f Zp[4] = {{Za.x,Za.y},{Za.z,Za.w},{Zb.x,Zb.y},{Zb.z,Zb.w}};

    // window byte layout: w[k] = x-position x0-2+k (mod 200), k = 0..11
    const int xL = (x0 == 0) ? (Dn - 2) : (x0 - 2);       // f2 covers w0,w1
    const int xR = (x0 == Dn - 8) ? 0 : (x0 + 8);         // f2 covers w10,w11

    float fxa[8] = {0,0,0,0,0,0,0,0};
    float fya[8] = {0,0,0,0,0,0,0,0};
    float fza[8] = {0,0,0,0,0,0,0,0};

    for (int i2 = 0; i2 < 5; ++i2) {
        int zz = zi + i2 - 2; zz += (zz < 0) ? Dn : 0; zz -= (zz >= Dn) ? Dn : 0;
        const int zbase = zz * DD;
        for (int i3 = 0; i3 < 5; ++i3) {
            int yy = yj + i3 - 2; yy += (yy < 0) ? Dn : 0; yy -= (yy >= Dn) ? Dn : 0;
            const int rowb = zbase + yy * Dn;
            const bool ctr = (i2 == 2) && (i3 == 2);

            // 12-float windows, exact coverage: f2 + f4 + f4 + f2 per array
            const v2f    wxL = *reinterpret_cast<const v2f*>(gx + rowb + xL);
            const float4 wxA = *reinterpret_cast<const float4*>(gx + rowb + x0);
            const float4 wxB = *reinterpret_cast<const float4*>(gx + rowb + x0 + 4);
            const v2f    wxR = *reinterpret_cast<const v2f*>(gx + rowb + xR);
            const v2f    wyL = *reinterpret_cast<const v2f*>(gy + rowb + xL);
            const float4 wyA = *reinterpret_cast<const float4*>(gy + rowb + x0);
            const float4 wyB = *reinterpret_cast<const float4*>(gy + rowb + x0 + 4);
            const v2f    wyR = *reinterpret_cast<const v2f*>(gy + rowb + xR);
            const v2f    wzL = *reinterpret_cast<const v2f*>(gz + rowb + xL);
            const float4 wzA = *reinterpret_cast<const float4*>(gz + rowb + x0);
            const float4 wzB = *reinterpret_cast<const float4*>(gz + rowb + x0 + 4);
            const v2f    wzR = *reinterpret_cast<const v2f*>(gz + rowb + xR);

            // shifted packed views sv[k] = {w[k], w[k+1]}, k = 0..10 (compile-time indexed)
            v2f svx[11], svy[11], svz[11];
            svx[0]=wxL; svx[1]=(v2f){wxL.y,wxA.x}; svx[2]=(v2f){wxA.x,wxA.y}; svx[3]=(v2f){wxA.y,wxA.z};
            svx[4]=(v2f){wxA.z,wxA.w}; svx[5]=(v2f){wxA.w,wxB.x}; svx[6]=(v2f){wxB.x,wxB.y};
            svx[7]=(v2f){wxB.y,wxB.z}; svx[8]=(v2f){wxB.z,wxB.w}; svx[9]=(v2f){wxB.w,wxR.x}; svx[10]=wxR;
            svy[0]=wyL; svy[1]=(v2f){wyL.y,wyA.x}; svy[2]=(v2f){wyA.x,wyA.y}; svy[3]=(v2f){wyA.y,wyA.z};
            svy[4]=(v2f){wyA.z,wyA.w}; svy[5]=(v2f){wyA.w,wyB.x}; svy[6]=(v2f){wyB.x,wyB.y};
            svy[7]=(v2f){wyB.y,wyB.z}; svy[8]=(v2f){wyB.z,wyB.w}; svy[9]=(v2f){wyB.w,wyR.x}; svy[10]=wyR;
            svz[0]=wzL; svz[1]=(v2f){wzL.y,wzA.x}; svz[2]=(v2f){wzA.x,wzA.y}; svz[3]=(v2f){wzA.y,wzA.z};
            svz[4]=(v2f){wzA.z,wzA.w}; svz[5]=(v2f){wzA.w,wzB.x}; svz[6]=(v2f){wzB.x,wzB.y};
            svz[7]=(v2f){wzB.y,wzB.z}; svz[8]=(v2f){wzB.z,wzB.w}; svz[9]=(v2f){wzB.w,wzR.x}; svz[10]=wzR;

            // ---- fast path: packed screening only (min of sq over the row) ----
            v2f mn = (v2f){1e30f, 1e30f};
            #pragma unroll
            for (int cp = 0; cp < 4; ++cp) {
                #pragma unroll
                for (int o = 0; o < 5; ++o) {
                    if (o == 2) continue;      // o==2 units handled below (self-pair on ctr row)
                    const int k = 2*cp + o;
                    const v2f dx = Xp[cp] - svx[k];
                    const v2f dy = Yp[cp] - svy[k];
                    const v2f dz = Zp[cp] - svz[k];
                    v2f sq = dx*dx; sq += dy*dy; sq += dz*dz;
                    mn.x = fminf(mn.x, sq.x);
                    mn.y = fminf(mn.y, sq.y);
                }
            }
            if (!ctr) {   // uniform branch: o==2 units, skipped entirely on the self row
                #pragma unroll
                for (int cp = 0; cp < 4; ++cp) {
                    const int k = 2*cp + 2;
                    const v2f dx = Xp[cp] - svx[k];
                    const v2f dy = Yp[cp] - svy[k];
                    const v2f dz = Zp[cp] - svz[k];
                    v2f sq = dx*dx; sq += dy*dy; sq += dz*dz;
                    mn.x = fminf(mn.x, sq.x);
                    mn.y = fminf(mn.y, sq.y);
                }
            }

            // ---- rare slow path: exact reference math for this row ----
            if (mn.x < THR || mn.y < THR) {
                #pragma unroll
                for (int c = 0; c < 8; ++c) {
                    #pragma unroll
                    for (int o = 0; o < 5; ++o) {
                        const int k = c + o;
                        const float wx = WK(wxL, wxA, wxB, wxR, k);
                        const float wy = WK(wyL, wyA, wyB, wyR, k);
                        const float wz = WK(wzL, wzA, wzB, wzR, k);
                        const float Xc = (c & 1) ? Xp[c>>1].y : Xp[c>>1].x;
                        const float Yc = (c & 1) ? Yp[c>>1].y : Yp[c>>1].x;
                        const float Zc = (c & 1) ? Zp[c>>1].y : Zp[c>>1].x;
                        const float dx = Xc - wx;
                        const float dy = Yc - wy;
                        const float dz = Zc - wz;
                        const float sq = dx*dx + dy*dy + dz*dz;
                        if (sq < THR) {
                            const float dist = sqrtf(sq);
                            if (dist < 0.1f) {
                                const float d = fmaxf(dist, 1e-4f);
                                int nxi = x0 + c + o - 2;
                                nxi += (nxi < 0) ? Dn : 0;
                                nxi -= (nxi >= Dn) ? Dn : 0;
                                const int gi = rowb + nxi;
                                const float dvx = gvx[cbase + c] - gvx[gi];
                                const float dvy = gvy[cbase + c] - gvy[gi];
                                const float dvz = gvz[cbase + c] - gvz[gi];
                                const float vn = (dvx*dx + dvy*dy + dvz*dz) / d;
                                const float coef = 2.0f * (600000.0f*(dist - 0.1f) + ETAf*vn) / d;
                                fxa[c] += coef * dx;
                                fya[c] += coef * dy;
                                fza[c] += coef * dz;
                            }
                        }
                    }
                }
            }
        }
    }

    // ---- velocities + mask loaded only now (frees VGPRs during main loop) ----
    const float4 VXa = *reinterpret_cast<const float4*>(gvx + cbase);
    const float4 VXb = *reinterpret_cast<const float4*>(gvx + cbase + 4);
    const float4 VYa = *reinterpret_cast<const float4*>(gvy + cbase);
    const float4 VYb = *reinterpret_cast<const float4*>(gvy + cbase + 4);
    const float4 VZa = *reinterpret_cast<const float4*>(gvz + cbase);
    const float4 VZb = *reinterpret_cast<const float4*>(gvz + cbase + 4);
    const float4 Ma  = *reinterpret_cast<const float4*>(gm  + cbase);
    const float4 Mb  = *reinterpret_cast<const float4*>(gm  + cbase + 4);

    float ox[8], oy[8], oz[8], ovx[8], ovy[8], ovz[8];
    #pragma unroll
    for (int c = 0; c < 8; ++c) {
        const float X = (c & 1) ? Xp[c>>1].y : Xp[c>>1].x;
        const float Y = (c & 1) ? Yp[c>>1].y : Yp[c>>1].x;
        const float Z = (c & 1) ? Zp[c>>1].y : Zp[c>>1].x;
        const float VX = (c < 4) ? C4(VXa, c) : C4(VXb, (c)-4);
        const float VY = (c < 4) ? C4(VYa, c) : C4(VYb, (c)-4);
        const float VZ = (c < 4) ? C4(VZa, c) : C4(VZb, (c)-4);
        const float M  = (c < 4) ? C4(Ma,  c) : C4(Mb,  (c)-4);

        float fxb = 0.f, fyb = 0.f, fzb = 0.f;
        if (X > 0.1f && X < 0.15f) fxb = 600000.0f * (0.15f - X) - ETAf * VX;
        if (X > 9.9f)              fxb = -600000.0f * (((X - 10.0f) + 0.05f) + 0.05f) - ETAf * VX;
        if (Y > 0.1f && Y < 0.15f) fyb = 600000.0f * (0.15f - Y) - ETAf * VY;
        if (Y > 9.9f)              fyb = -600000.0f * (((Y - 10.0f) + 0.05f) + 0.05f) - ETAf * VY;
        if (Z > 0.1f && Z < 0.15f) fzb = 600000.0f * (0.15f - Z) - ETAf * VZ;
        if (Z > 9.9f)              fzb = -600000.0f * (((Z - 10.0f) + 0.05f) + 0.05f) - ETAf * VZ;

        const float am = dtOverPm * M;
        ovx[c] = VX + am * ((-fxa[c]) + fxb);
        ovy[c] = VY + am * ((-fya[c]) + fyb);
        ovz[c] = VZ + am * ((gravTerm - fza[c]) + fzb);
        ox[c] = X + 1e-4f * ovx[c];
        oy[c] = Y + 1e-4f * ovy[c];
        oz[c] = Z + 1e-4f * ovz[c];
    }

    // nontemporal stores (native clang vector type): keep the 192 MB output
    // stream out of L2/L3
    #define ST(arr, base) \
        __builtin_nontemporal_store((v4f){(arr)[0],(arr)[1],(arr)[2],(arr)[3]}, \
                                    reinterpret_cast<v4f*>(out + (base) + cbase)); \
        __builtin_nontemporal_store((v4f){(arr)[4],(arr)[5],(arr)[6],(arr)[7]}, \
                                    reinterpret_cast<v4f*>(out + (base) + cbase + 4));
    ST(ox,  0L * NC)
    ST(oy,  1L * NC)
    ST(oz,  2L * NC)
    ST(ovx, 3L * NC)
    ST(ovy, 4L * NC)
    ST(ovz, 5L * NC)
    #undef ST
}

extern "C" void kernel_launch(void* const* d_in, const int* in_sizes, int n_in,
                              void* d_out, int out_size, void* d_ws, size_t ws_size,
                              hipStream_t stream) {
    const float* gx  = (const float*)d_in[0];
    const float* gy  = (const float*)d_in[1];
    const float* gz  = (const float*)d_in[2];
    const float* gvx = (const float*)d_in[3];
    const float* gvy = (const float*)d_in[4];
    const float* gvz = (const float*)d_in[5];
    const float* gm  = (const float*)d_in[6];
    float* out = (float*)d_out;

    const double KN  = 600000.0;
    const double PM  = 4.0 / 3.0 * 3.1415 * std::pow(0.05, 3) * 2700.0;
    const double alpha = -std::log(0.5) / M_PI;
    const double gamma = alpha / std::sqrt(alpha * alpha + 1.0);
    const double ETA = 2.0 * gamma * std::sqrt(KN * PM);

    const float ETAf     = (float)ETA;
    const float dtOverPm = (float)(0.0001 / PM);
    const float gravTerm = (float)(-9.8 * PM);

    dem_step_kernel<<<NBLK, 256, 0, stream>>>(gx, gy, gz, gvx, gvy, gvz, gm, out,
                                              ETAf, dtOverPm, gravTerm);
}

// Round 5
// 214.242 us; speedup vs baseline: 3.9985x; 1.0317x over previous
//
#include <hip/hip_runtime.h>
#include <cmath>

#ifndef M_PI
#define M_PI 3.14159265358979323846
#endif

typedef float v2f __attribute__((ext_vector_type(2)));
typedef float v4f __attribute__((ext_vector_type(4)));

constexpr int Dn = 200;
constexpr int DD = Dn * Dn;        // 40000
constexpr int NC = Dn * Dn * Dn;   // 8,000,000
constexpr int TPR = 25;            // threads per row (8 cells each)
constexpr int RPB = 10;            // rows per block (250 live threads)
constexpr int NBLK = (Dn * Dn) / RPB;  // 4000, divisible by 8 -> bijective XCD swizzle
constexpr float THR = 0.0100001f;  // conservative prefilter on sq (exact test in slow path)

// compile-time component selectors (fold to subregister access under full unroll)
#define C4(v,c) ((c)==0?(v).x:(c)==1?(v).y:(c)==2?(v).z:(v).w)
#define WK(L,A,B,R,k) ((k)==0?(L).x:(k)==1?(L).y: \
                       ((k)>=2&&(k)<=5)?C4(A,(k)-2): \
                       ((k)>=6&&(k)<=9)?C4(B,(k)-6): \
                       ((k)==10?(R).x:(R).y))

// packed squared-distance of 2 cell/neighbor pairs: 6 VOP3P instructions.
// nX/nY/nZ are NEGATED center positions; sign of d is irrelevant (squared).
__device__ __forceinline__ v2f psq(v2f nX, v2f nY, v2f nZ, v2f wx, v2f wy, v2f wz) {
    v2f dx, dy, dz, s;
    asm("v_pk_add_f32 %0, %1, %2" : "=v"(dx) : "v"(wx), "v"(nX));
    asm("v_pk_add_f32 %0, %1, %2" : "=v"(dy) : "v"(wy), "v"(nY));
    asm("v_pk_add_f32 %0, %1, %2" : "=v"(dz) : "v"(wz), "v"(nZ));
    asm("v_pk_mul_f32 %0, %1, %1" : "=v"(s)  : "v"(dx));
    asm("v_pk_fma_f32 %0, %1, %1, %0" : "+v"(s) : "v"(dy));
    asm("v_pk_fma_f32 %0, %1, %1, %0" : "+v"(s) : "v"(dz));
    return s;
}

__global__ __launch_bounds__(256, 2) void dem_step_kernel(
    const float* __restrict__ gx, const float* __restrict__ gy, const float* __restrict__ gz,
    const float* __restrict__ gvx, const float* __restrict__ gvy, const float* __restrict__ gvz,
    const float* __restrict__ gm, float* __restrict__ out,
    float ETAf, float dtOverPm, float gravTerm)
{
    const int t = threadIdx.x;
    if (t >= TPR * RPB) return;

    const int bid = blockIdx.x;
    const int sb = (bid & 7) * (NBLK / 8) + (bid >> 3);   // XCD-contiguous z-slabs

    const int rowid = sb * RPB + t / TPR;
    const int x0 = (t % TPR) * 8;
    const int zi = rowid / Dn;
    const int yj = rowid % Dn;
    const int cbase = rowid * Dn + x0;

    // ---- negated center packs ----
    const v4f Xa = *reinterpret_cast<const v4f*>(gx + cbase);
    const v4f Xb = *reinterpret_cast<const v4f*>(gx + cbase + 4);
    const v4f Ya = *reinterpret_cast<const v4f*>(gy + cbase);
    const v4f Yb = *reinterpret_cast<const v4f*>(gy + cbase + 4);
    const v4f Za = *reinterpret_cast<const v4f*>(gz + cbase);
    const v4f Zb = *reinterpret_cast<const v4f*>(gz + cbase + 4);

    // even cell-pairs {0,1},{2,3},{4,5},{6,7}
    v2f nXe[4] = {{-Xa.x,-Xa.y},{-Xa.z,-Xa.w},{-Xb.x,-Xb.y},{-Xb.z,-Xb.w}};
    v2f nYe[4] = {{-Ya.x,-Ya.y},{-Ya.z,-Ya.w},{-Yb.x,-Yb.y},{-Yb.z,-Yb.w}};
    v2f nZe[4] = {{-Za.x,-Za.y},{-Za.z,-Za.w},{-Zb.x,-Zb.y},{-Zb.z,-Zb.w}};
    // odd cell-pairs {1,2},{3,4},{5,6}
    v2f nXo[3] = {{-Xa.y,-Xa.z},{-Xa.w,-Xb.x},{-Xb.y,-Xb.z}};
    v2f nYo[3] = {{-Ya.y,-Ya.z},{-Ya.w,-Yb.x},{-Yb.y,-Yb.z}};
    v2f nZo[3] = {{-Za.y,-Za.z},{-Za.w,-Zb.x},{-Zb.y,-Zb.z}};

    const int xL = (x0 == 0) ? (Dn - 2) : (x0 - 2);
    const int xR = (x0 == Dn - 8) ? 0 : (x0 + 8);

    float fxa[8] = {0,0,0,0,0,0,0,0};
    float fya[8] = {0,0,0,0,0,0,0,0};
    float fza[8] = {0,0,0,0,0,0,0,0};

    for (int i2 = 0; i2 < 5; ++i2) {
        int zz = zi + i2 - 2; zz += (zz < 0) ? Dn : 0; zz -= (zz >= Dn) ? Dn : 0;
        const int zbase = zz * DD;
        for (int i3 = 0; i3 < 5; ++i3) {
            int yy = yj + i3 - 2; yy += (yy < 0) ? Dn : 0; yy -= (yy >= Dn) ? Dn : 0;
            const int rowb = zbase + yy * Dn;
            const bool ctr = (i2 == 2) && (i3 == 2);

            // 12-float windows; natural even-aligned pairs W[j] = {w[2j], w[2j+1]}
            const v2f wxL = *reinterpret_cast<const v2f*>(gx + rowb + xL);
            const v4f wxA = *reinterpret_cast<const v4f*>(gx + rowb + x0);
            const v4f wxB = *reinterpret_cast<const v4f*>(gx + rowb + x0 + 4);
            const v2f wxR = *reinterpret_cast<const v2f*>(gx + rowb + xR);
            const v2f wyL = *reinterpret_cast<const v2f*>(gy + rowb + xL);
            const v4f wyA = *reinterpret_cast<const v4f*>(gy + rowb + x0);
            const v4f wyB = *reinterpret_cast<const v4f*>(gy + rowb + x0 + 4);
            const v2f wyR = *reinterpret_cast<const v2f*>(gy + rowb + xR);
            const v2f wzL = *reinterpret_cast<const v2f*>(gz + rowb + xL);
            const v4f wzA = *reinterpret_cast<const v4f*>(gz + rowb + x0);
            const v4f wzB = *reinterpret_cast<const v4f*>(gz + rowb + x0 + 4);
            const v2f wzR = *reinterpret_cast<const v2f*>(gz + rowb + xR);

            v2f Px[6] = {wxL, {wxA.x,wxA.y}, {wxA.z,wxA.w}, {wxB.x,wxB.y}, {wxB.z,wxB.w}, wxR};
            v2f Py[6] = {wyL, {wyA.x,wyA.y}, {wyA.z,wyA.w}, {wyB.x,wyB.y}, {wyB.z,wyB.w}, wyR};
            v2f Pz[6] = {wzL, {wzA.x,wzA.y}, {wzA.z,wzA.w}, {wzB.x,wzB.y}, {wzB.z,wzB.w}, wzR};

            // ---- packed screen: 18 units + 4 scalar leftovers, 4 rotating mins ----
            float mm[4] = {1e30f, 1e30f, 1e30f, 1e30f};
            #pragma unroll
            for (int c = 0; c < 4; ++c) {                 // even pairs, o=0 and o=4
                const v2f s0 = psq(nXe[c],nYe[c],nZe[c], Px[c],  Py[c],  Pz[c]);
                const v2f s4 = psq(nXe[c],nYe[c],nZe[c], Px[c+2],Py[c+2],Pz[c+2]);
                mm[c]       = fminf(fminf(s0.x, s0.y), mm[c]);
                mm[(c+1)&3] = fminf(fminf(s4.x, s4.y), mm[(c+1)&3]);
            }
            if (!ctr) {                                    // even pairs, o=2 (self on ctr row)
                #pragma unroll
                for (int c = 0; c < 4; ++c) {
                    const v2f s2 = psq(nXe[c],nYe[c],nZe[c], Px[c+1],Py[c+1],Pz[c+1]);
                    mm[(c+2)&3] = fminf(fminf(s2.x, s2.y), mm[(c+2)&3]);
                }
            }
            #pragma unroll
            for (int c = 0; c < 3; ++c) {                  // odd pairs, o=1 and o=3
                const v2f s1 = psq(nXo[c],nYo[c],nZo[c], Px[c+1],Py[c+1],Pz[c+1]);
                const v2f s3 = psq(nXo[c],nYo[c],nZo[c], Px[c+2],Py[c+2],Pz[c+2]);
                mm[c]       = fminf(fminf(s1.x, s1.y), mm[c]);
                mm[(c+2)&3] = fminf(fminf(s3.x, s3.y), mm[(c+2)&3]);
            }
            {   // scalar leftovers: cell0 o=1,3 ; cell7 o=1,3
                float dx = Px[0].y + nXe[0].x, dy = Py[0].y + nYe[0].x, dz = Pz[0].y + nZe[0].x;
                mm[0] = fminf(fmaf(dz,dz,fmaf(dy,dy,dx*dx)), mm[0]);
                dx = Px[1].y + nXe[0].x; dy = Py[1].y + nYe[0].x; dz = Pz[1].y + nZe[0].x;
                mm[1] = fminf(fmaf(dz,dz,fmaf(dy,dy,dx*dx)), mm[1]);
                dx = Px[4].x + nXe[3].y; dy = Py[4].x + nYe[3].y; dz = Pz[4].x + nZe[3].y;
                mm[2] = fminf(fmaf(dz,dz,fmaf(dy,dy,dx*dx)), mm[2]);
                dx = Px[5].x + nXe[3].y; dy = Py[5].x + nYe[3].y; dz = Pz[5].x + nZe[3].y;
                mm[3] = fminf(fmaf(dz,dz,fmaf(dy,dy,dx*dx)), mm[3]);
            }

            // ---- rare slow path: exact reference math for this row ----
            if (fminf(fminf(mm[0],mm[1]), fminf(mm[2],mm[3])) < THR) {
                #pragma unroll
                for (int c = 0; c < 8; ++c) {
                    const float Xc = -((c & 1) ? nXe[c>>1].y : nXe[c>>1].x);
                    const float Yc = -((c & 1) ? nYe[c>>1].y : nYe[c>>1].x);
                    const float Zc = -((c & 1) ? nZe[c>>1].y : nZe[c>>1].x);
                    #pragma unroll
                    for (int o = 0; o < 5; ++o) {
                        const int k = c + o;
                        const float wx = WK(wxL, wxA, wxB, wxR, k);
                        const float wy = WK(wyL, wyA, wyB, wyR, k);
                        const float wz = WK(wzL, wzA, wzB, wzR, k);
                        const float dx = Xc - wx;
                        const float dy = Yc - wy;
                        const float dz = Zc - wz;
                        const float sq = dx*dx + dy*dy + dz*dz;
                        if (sq < THR) {
                            const float dist = sqrtf(sq);
                            if (dist < 0.1f) {
                                const float d = fmaxf(dist, 1e-4f);
                                int nxi = x0 + c + o - 2;
                                nxi += (nxi < 0) ? Dn : 0;
                                nxi -= (nxi >= Dn) ? Dn : 0;
                                const int gi = rowb + nxi;
                                const float dvx = gvx[cbase + c] - gvx[gi];
                                const float dvy = gvy[cbase + c] - gvy[gi];
                                const float dvz = gvz[cbase + c] - gvz[gi];
                                const float vn = (dvx*dx + dvy*dy + dvz*dz) / d;
                                const float coef = 2.0f * (600000.0f*(dist - 0.1f) + ETAf*vn) / d;
                                fxa[c] += coef * dx;
                                fya[c] += coef * dy;
                                fza[c] += coef * dz;
                            }
                        }
                    }
                }
            }
        }
    }

    // ---- velocities + mask loaded only now ----
    const v4f VXa = *reinterpret_cast<const v4f*>(gvx + cbase);
    const v4f VXb = *reinterpret_cast<const v4f*>(gvx + cbase + 4);
    const v4f VYa = *reinterpret_cast<const v4f*>(gvy + cbase);
    const v4f VYb = *reinterpret_cast<const v4f*>(gvy + cbase + 4);
    const v4f VZa = *reinterpret_cast<const v4f*>(gvz + cbase);
    const v4f VZb = *reinterpret_cast<const v4f*>(gvz + cbase + 4);
    const v4f Ma  = *reinterpret_cast<const v4f*>(gm  + cbase);
    const v4f Mb  = *reinterpret_cast<const v4f*>(gm  + cbase + 4);

    float ox[8], oy[8], oz[8], ovx[8], ovy[8], ovz[8];
    #pragma unroll
    for (int c = 0; c < 8; ++c) {
        const float X = -((c & 1) ? nXe[c>>1].y : nXe[c>>1].x);
        const float Y = -((c & 1) ? nYe[c>>1].y : nYe[c>>1].x);
        const float Z = -((c & 1) ? nZe[c>>1].y : nZe[c>>1].x);
        const float VX = (c < 4) ? C4(VXa, c) : C4(VXb, (c)-4);
        const float VY = (c < 4) ? C4(VYa, c) : C4(VYb, (c)-4);
        const float VZ = (c < 4) ? C4(VZa, c) : C4(VZb, (c)-4);
        const float M  = (c < 4) ? C4(Ma,  c) : C4(Mb,  (c)-4);

        float fxb = 0.f, fyb = 0.f, fzb = 0.f;
        if (X > 0.1f && X < 0.15f) fxb = 600000.0f * (0.15f - X) - ETAf * VX;
        if (X > 9.9f)              fxb = -600000.0f * (((X - 10.0f) + 0.05f) + 0.05f) - ETAf * VX;
        if (Y > 0.1f && Y < 0.15f) fyb = 600000.0f * (0.15f - Y) - ETAf * VY;
        if (Y > 9.9f)              fyb = -600000.0f * (((Y - 10.0f) + 0.05f) + 0.05f) - ETAf * VY;
        if (Z > 0.1f && Z < 0.15f) fzb = 600000.0f * (0.15f - Z) - ETAf * VZ;
        if (Z > 9.9f)              fzb = -600000.0f * (((Z - 10.0f) + 0.05f) + 0.05f) - ETAf * VZ;

        const float am = dtOverPm * M;
        ovx[c] = VX + am * ((-fxa[c]) + fxb);
        ovy[c] = VY + am * ((-fya[c]) + fyb);
        ovz[c] = VZ + am * ((gravTerm - fza[c]) + fzb);
        ox[c] = X + 1e-4f * ovx[c];
        oy[c] = Y + 1e-4f * ovy[c];
        oz[c] = Z + 1e-4f * ovz[c];
    }

    #define ST(arr, base) \
        __builtin_nontemporal_store((v4f){(arr)[0],(arr)[1],(arr)[2],(arr)[3]}, \
                                    reinterpret_cast<v4f*>(out + (base) + cbase)); \
        __builtin_nontemporal_store((v4f){(arr)[4],(arr)[5],(arr)[6],(arr)[7]}, \
                                    reinterpret_cast<v4f*>(out + (base) + cbase + 4));
    ST(ox,  0L * NC)
    ST(oy,  1L * NC)
    ST(oz,  2L * NC)
    ST(ovx, 3L * NC)
    ST(ovy, 4L * NC)
    ST(ovz, 5L * NC)
    #undef ST
}

extern "C" void kernel_launch(void* const* d_in, const int* in_sizes, int n_in,
                              void* d_out, int out_size, void* d_ws, size_t ws_size,
                              hipStream_t stream) {
    const float* gx  = (const float*)d_in[0];
    const float* gy  = (const float*)d_in[1];
    const float* gz  = (const float*)d_in[2];
    const float* gvx = (const float*)d_in[3];
    const float* gvy = (const float*)d_in[4];
    const float* gvz = (const float*)d_in[5];
    const float* gm  = (const float*)d_in[6];
    float* out = (float*)d_out;

    const double KN  = 600000.0;
    const double PM  = 4.0 / 3.0 * 3.1415 * std::pow(0.05, 3) * 2700.0;
    const double alpha = -std::log(0.5) / M_PI;
    const double gamma = alpha / std::sqrt(alpha * alpha + 1.0);
    const double ETA = 2.0 * gamma * std::sqrt(KN * PM);

    const float ETAf     = (float)ETA;
    const float dtOverPm = (float)(0.0001 / PM);
    const float gravTerm = (float)(-9.8 * PM);

    dem_step_kernel<<<NBLK, 256, 0, stream>>>(gx, gy, gz, gvx, gvy, gvz, gm, out,
                                              ETAf, dtOverPm, gravTerm);
}